// Round 4
// baseline (627.548 us; speedup 1.0000x reference)
//
#include <hip/hip_runtime.h>

#define B_ 8192
#define D_ 1024
#define O_ 1024
#define G_ 512
#define H_ 2048
#define E_ 8
#define ROWSP (B_ * 2 + E_ * 128)   // padded routed rows = 17408
#define TAU 0.01f

typedef unsigned short u16;
using f32x4 = __attribute__((ext_vector_type(4))) float;
using s16x8 = __attribute__((ext_vector_type(8))) short;

__device__ __forceinline__ u16 f2bf(float f) {
  union { float f; unsigned u; } v; v.f = f;
  unsigned r = v.u + 0x7FFFu + ((v.u >> 16) & 1u);
  return (u16)(r >> 16);
}
__device__ __forceinline__ float bf2f(u16 h) {
  union { unsigned u; float f; } v; v.u = ((unsigned)h) << 16; return v.f;
}
__device__ __forceinline__ void gload16(const void* g, void* l) {
  __builtin_amdgcn_global_load_lds(
      (const __attribute__((address_space(1))) unsigned int*)g,
      (__attribute__((address_space(3))) unsigned int*)l, 16, 0, 0);
}
// XCD-aware swizzle: hardware bid -> work id; XCD(bid)=bid%8 gets contiguous works.
__device__ __forceinline__ int xcd_swz(int bid, int nwg) {
  return (bid & 7) * (nwg >> 3) + (bid >> 3);
}
// LDS tile layout [half][ks][row]: u16 index of fragment read.
// half = which 64-row half, ks = lane>>4 (16B k-chunk), row = i*16 + (lane&15).
__device__ __forceinline__ int frag_idx(int half, int lane, int i) {
  return half * 2048 + (lane >> 4) * 512 + (i * 16 + (lane & 15)) * 8;
}

// ---------- cast x -> bf16 hi/lo ----------
__global__ __launch_bounds__(256) void k_cast_x(const float* __restrict__ x,
                                                u16* __restrict__ xhi,
                                                u16* __restrict__ xlo) {
  int t = blockIdx.x * 256 + threadIdx.x;  // < B_*D_/4
  float4 v = ((const float4*)x)[t];
  u16 h0 = f2bf(v.x), h1 = f2bf(v.y), h2 = f2bf(v.z), h3 = f2bf(v.w);
  ushort4 hi; hi.x = h0; hi.y = h1; hi.z = h2; hi.w = h3;
  ushort4 lo;
  lo.x = f2bf(v.x - bf2f(h0)); lo.y = f2bf(v.y - bf2f(h1));
  lo.z = f2bf(v.z - bf2f(h2)); lo.w = f2bf(v.w - bf2f(h3));
  ((ushort4*)xhi)[t] = hi; ((ushort4*)xlo)[t] = lo;
}

// ---------- transpose+cast: src [R][C] f32 -> dst [C][R] bf16 (hi, optional lo) ----------
__global__ __launch_bounds__(256) void k_transpose_cast(const float* __restrict__ src,
                                                        u16* __restrict__ dhi,
                                                        u16* __restrict__ dlo,
                                                        int R, int C) {
  __shared__ float tile[32][33];
  size_t bofs = (size_t)blockIdx.z * R * C;
  src += bofs; dhi += bofs; if (dlo) dlo += bofs;
  int tx = threadIdx.x & 31, ty = threadIdx.x >> 5;
  int c0 = blockIdx.x * 32, r0 = blockIdx.y * 32;
#pragma unroll
  for (int p = 0; p < 4; ++p) {
    int r = ty + p * 8;
    tile[r][tx] = src[(size_t)(r0 + r) * C + c0 + tx];
  }
  __syncthreads();
#pragma unroll
  for (int p = 0; p < 4; ++p) {
    int r = ty + p * 8;  // local C index
    float v = tile[tx][r];
    size_t o = (size_t)(c0 + r) * R + r0 + tx;
    dhi[o] = f2bf(v);
    if (dlo) dlo[o] = f2bf(v - bf2f(f2bf(v)));
  }
}

// ---------- gate GEMM1: G1 = relu(x @ Wg1 + bg1), 3-pass split bf16, f32 out ----------
__global__ __launch_bounds__(256) void k_gate_gemm1(const u16* __restrict__ xhi,
                                                    const u16* __restrict__ xlo,
                                                    const u16* __restrict__ whi,
                                                    const u16* __restrict__ wlo,
                                                    const float* __restrict__ bg1,
                                                    float* __restrict__ G1) {
  __shared__ u16 Ah[4096], Al[4096], Bh[4096], Bl[4096];
  int work = xcd_swz(blockIdx.x, (G_ / 128) * (B_ / 128));
  int m0 = (work >> 2) * 128, n0 = (work & 3) * 128;
  int t = threadIdx.x;
  int wave = t >> 6, lane = t & 63;
  int wm = wave >> 1, wn = wave & 1;

  const f32x4 z = {0.f, 0.f, 0.f, 0.f};
  f32x4 acc[4][4];
#pragma unroll
  for (int i = 0; i < 4; ++i)
#pragma unroll
    for (int j = 0; j < 4; ++j) acc[i][j] = z;

  int r6 = t & 63, ks8 = (t >> 6) * 8;
  const u16* xh0 = xhi + (size_t)(m0 + r6) * D_ + ks8;
  const u16* xh1 = xhi + (size_t)(m0 + 64 + r6) * D_ + ks8;
  const u16* xl0 = xlo + (size_t)(m0 + r6) * D_ + ks8;
  const u16* xl1 = xlo + (size_t)(m0 + 64 + r6) * D_ + ks8;
  const u16* wh0 = whi + (size_t)(n0 + r6) * D_ + ks8;
  const u16* wh1 = whi + (size_t)(n0 + 64 + r6) * D_ + ks8;
  const u16* wl0 = wlo + (size_t)(n0 + r6) * D_ + ks8;
  const u16* wl1 = wlo + (size_t)(n0 + 64 + r6) * D_ + ks8;

  for (int k0 = 0; k0 < D_; k0 += 32) {
    gload16(xh0 + k0, &Ah[t * 8]); gload16(xh1 + k0, &Ah[2048 + t * 8]);
    gload16(xl0 + k0, &Al[t * 8]); gload16(xl1 + k0, &Al[2048 + t * 8]);
    gload16(wh0 + k0, &Bh[t * 8]); gload16(wh1 + k0, &Bh[2048 + t * 8]);
    gload16(wl0 + k0, &Bl[t * 8]); gload16(wl1 + k0, &Bl[2048 + t * 8]);
    __syncthreads();
    s16x8 ah[4], al[4], bh[4], bl[4];
#pragma unroll
    for (int i = 0; i < 4; ++i) {
      ah[i] = *(const s16x8*)&Ah[frag_idx(wm, lane, i)];
      al[i] = *(const s16x8*)&Al[frag_idx(wm, lane, i)];
      bh[i] = *(const s16x8*)&Bh[frag_idx(wn, lane, i)];
      bl[i] = *(const s16x8*)&Bl[frag_idx(wn, lane, i)];
    }
#pragma unroll
    for (int i = 0; i < 4; ++i)
#pragma unroll
      for (int j = 0; j < 4; ++j) {
        acc[i][j] = __builtin_amdgcn_mfma_f32_16x16x32_bf16(ah[i], bh[j], acc[i][j], 0, 0, 0);
        acc[i][j] = __builtin_amdgcn_mfma_f32_16x16x32_bf16(ah[i], bl[j], acc[i][j], 0, 0, 0);
        acc[i][j] = __builtin_amdgcn_mfma_f32_16x16x32_bf16(al[i], bh[j], acc[i][j], 0, 0, 0);
      }
    __syncthreads();
  }
#pragma unroll
  for (int j = 0; j < 4; ++j) {
    int col = n0 + wn * 64 + j * 16 + (lane & 15);
    float bias = bg1[col];
#pragma unroll
    for (int i = 0; i < 4; ++i)
#pragma unroll
      for (int q = 0; q < 4; ++q) {
        int row = m0 + wm * 64 + i * 16 + (lane >> 4) * 4 + q;
        float v = acc[i][j][q] + bias;
        G1[(size_t)row * G_ + col] = v > 0.f ? v : 0.f;
      }
  }
}

// ---------- gate logits: L = G1 @ Wg2 + bg2 (fp32, wave per row) + near-tie flagging ----------
__global__ __launch_bounds__(256) void k_gate_logits(const float* __restrict__ G1,
                                                     const float* __restrict__ Wg2,
                                                     const float* __restrict__ bg2,
                                                     float* __restrict__ logits,
                                                     int* __restrict__ flaglist,
                                                     int* __restrict__ nflag) {
  int t = threadIdx.x, wave = t >> 6, lane = t & 63;
  int row = blockIdx.x * 4 + wave;

  float4 g0 = *(const float4*)(G1 + (size_t)row * G_ + lane * 8);
  float4 g1 = *(const float4*)(G1 + (size_t)row * G_ + lane * 8 + 4);
  float g[8] = {g0.x, g0.y, g0.z, g0.w, g1.x, g1.y, g1.z, g1.w};
  float p[8] = {0, 0, 0, 0, 0, 0, 0, 0};
#pragma unroll
  for (int cc = 0; cc < 8; ++cc) {
    int c = lane * 8 + cc;
    float4 w0 = *(const float4*)(Wg2 + c * 8);
    float4 w1 = *(const float4*)(Wg2 + c * 8 + 4);
    p[0] += g[cc] * w0.x; p[1] += g[cc] * w0.y; p[2] += g[cc] * w0.z; p[3] += g[cc] * w0.w;
    p[4] += g[cc] * w1.x; p[5] += g[cc] * w1.y; p[6] += g[cc] * w1.z; p[7] += g[cc] * w1.w;
  }
#pragma unroll
  for (int off = 32; off >= 1; off >>= 1)
#pragma unroll
    for (int e = 0; e < 8; ++e) p[e] += __shfl_xor(p[e], off);
  if (lane == 0) {
    float l1 = -1e30f, l2 = -1e30f, l3 = -1e30f;
#pragma unroll
    for (int e = 0; e < 8; ++e) {
      float v = p[e] + bg2[e];
      logits[(size_t)row * 8 + e] = v;
      if (v > l1) { l3 = l2; l2 = l1; l1 = v; }
      else if (v > l2) { l3 = l2; l2 = v; }
      else if (v > l3) { l3 = v; }
    }
    if (l2 - l3 < TAU) {
      int pos = atomicAdd(nflag, 1);
      flaglist[pos] = row;
    }
  }
}

// ---------- exact fp32 recompute for flagged rows (tree reduce, no atomics) ----------
__global__ __launch_bounds__(256) void k_gate_fixup(const float* __restrict__ x,
                                                    const float* __restrict__ Wg1,
                                                    const float* __restrict__ bg1,
                                                    const float* __restrict__ Wg2,
                                                    const float* __restrict__ bg2,
                                                    const int* __restrict__ flaglist,
                                                    const int* __restrict__ nflag,
                                                    float* __restrict__ logits) {
  __shared__ float xs[1024];
  __shared__ float red[256][9];
  int t = threadIdx.x;
  int n = *nflag;
  for (int i = blockIdx.x; i < n; i += gridDim.x) {
    int row = flaglist[i];
    ((float4*)xs)[t] = ((const float4*)(x + (size_t)row * D_))[t];
    __syncthreads();
    int c0 = t * 2;
    float h0 = 0.f, h1 = 0.f;
#pragma unroll 8
    for (int d = 0; d < D_; ++d) {
      float xv = xs[d];
      float2 w = *(const float2*)(Wg1 + (size_t)d * G_ + c0);
      h0 += xv * w.x; h1 += xv * w.y;
    }
    h0 += bg1[c0]; h1 += bg1[c0 + 1];
    h0 = h0 > 0.f ? h0 : 0.f; h1 = h1 > 0.f ? h1 : 0.f;
#pragma unroll
    for (int e = 0; e < 8; ++e)
      red[t][e] = h0 * Wg2[c0 * 8 + e] + h1 * Wg2[(c0 + 1) * 8 + e];
    __syncthreads();
    for (int s = 128; s >= 1; s >>= 1) {
      if (t < s) {
#pragma unroll
        for (int e = 0; e < 8; ++e) red[t][e] += red[t + s][e];
      }
      __syncthreads();
    }
    if (t < 8) logits[(size_t)row * 8 + t] = red[0][t] + bg2[t];
    __syncthreads();
  }
}

// ---------- final gate: softmax + top2 + weights + counts/entropy (thread per row) ----------
__global__ __launch_bounds__(256) void k_gate_final(const float* __restrict__ logits,
                                                    int* __restrict__ topidx,
                                                    float* __restrict__ wnorm,
                                                    int* __restrict__ counts,
                                                    float* __restrict__ entacc) {
  __shared__ int cnt_s[8];
  __shared__ float ent_s[4];
  int t = threadIdx.x;
  if (t < 8) cnt_s[t] = 0;
  __syncthreads();
  int row = blockIdx.x * 256 + t;
  float4 a = ((const float4*)logits)[(size_t)row * 2];
  float4 b = ((const float4*)logits)[(size_t)row * 2 + 1];
  float L[8] = {a.x, a.y, a.z, a.w, b.x, b.y, b.z, b.w};
  float m = L[0];
#pragma unroll
  for (int e = 1; e < 8; ++e) m = fmaxf(m, L[e]);
  float s[8], Z = 0.f;
#pragma unroll
  for (int e = 0; e < 8; ++e) { s[e] = expf(L[e] - m); Z += s[e]; }
  float inv = 1.f / Z;
  float sc[8];
#pragma unroll
  for (int e = 0; e < 8; ++e) sc[e] = s[e] * inv;
  int i1 = 0;
#pragma unroll
  for (int e = 1; e < 8; ++e) if (L[e] > L[i1]) i1 = e;
  int i2 = (i1 == 0) ? 1 : 0;
#pragma unroll
  for (int e = 0; e < 8; ++e) if (e != i1 && L[e] > L[i2]) i2 = e;
  float s1 = sc[i1], s2 = sc[i2];
  float denom = s1 + s2 + 1e-9f;
  topidx[row * 2] = i1; topidx[row * 2 + 1] = i2;
  wnorm[row * 2] = s1 / denom; wnorm[row * 2 + 1] = s2 / denom;
  atomicAdd(&cnt_s[i1], 1); atomicAdd(&cnt_s[i2], 1);
  float ent = 0.f;
#pragma unroll
  for (int e = 0; e < 8; ++e) ent -= sc[e] * logf(sc[e] + 1e-9f);
#pragma unroll
  for (int off = 32; off >= 1; off >>= 1) ent += __shfl_xor(ent, off);
  if ((t & 63) == 0) ent_s[t >> 6] = ent;
  __syncthreads();
  if (t == 0) atomicAdd(entacc, ent_s[0] + ent_s[1] + ent_s[2] + ent_s[3]);
  if (t < 8) atomicAdd(&counts[t], cnt_s[t]);
}

// ---------- scan: padded offsets + aux loss ----------
__global__ void k_scan(const int* __restrict__ counts, const float* __restrict__ entacc,
                       int* __restrict__ aoff, float* __restrict__ aux_out) {
  if (threadIdx.x == 0 && blockIdx.x == 0) {
    int off = 0; aoff[0] = 0;
    float ld[8]; float mean = 0.f;
    for (int e = 0; e < 8; ++e) {
      ld[e] = (float)counts[e] / (8192.0f + 1e-9f);
      mean += ld[e];
      off += ((counts[e] + 127) >> 7) << 7;
      aoff[e + 1] = off;
    }
    mean *= 0.125f;
    float var = 0.f;
    for (int e = 0; e < 8; ++e) { float d = ld[e] - mean; var += d * d; }
    var *= (1.0f / 7.0f);
    *aux_out = var + entacc[0] / 8192.0f;
  }
}

// ---------- scatter routing (+ per-(token,k) position record) ----------
__global__ __launch_bounds__(256) void k_scatter(const int* __restrict__ topidx,
                                                 const float* __restrict__ wnorm,
                                                 const int* __restrict__ aoff,
                                                 int* __restrict__ fill,
                                                 int* __restrict__ tok_list,
                                                 float* __restrict__ wroute,
                                                 int* __restrict__ pos_of) {
  int t = blockIdx.x * 256 + threadIdx.x;
  if (t >= B_ * 2) return;
  int e = topidx[t];
  int pos = aoff[e] + atomicAdd(&fill[e], 1);
  tok_list[pos] = t >> 1;
  wroute[pos] = wnorm[t];
  pos_of[t] = pos;
}

// ---------- expert GEMM1: h = relu(gather(x) @ W1[e] + b1[e]) -> bf16 (dbuf) ----------
__global__ __launch_bounds__(256) void k_egemm1(const u16* __restrict__ xhi,
                                                const u16* __restrict__ w1t,
                                                const float* __restrict__ b1v,
                                                const int* __restrict__ tok_list,
                                                const int* __restrict__ aoff,
                                                u16* __restrict__ hbuf) {
  __shared__ u16 As[2][4096], Bs[2][4096];
  int work = xcd_swz(blockIdx.x, (H_ / 128) * (ROWSP / 128));
  int rt = work >> 4;                 // row-tile (A-panel shared by 16 n-tiles)
  int n0 = (work & 15) * 128;
  int row0 = rt * 128;
  if (row0 >= aoff[8]) return;
  int e = 0;
  while (row0 >= aoff[e + 1]) ++e;
  int t = threadIdx.x, wave = t >> 6, lane = t & 63;
  int wm = wave >> 1, wn = wave & 1;
  const u16* w1e = w1t + (size_t)e * H_ * D_;

  int r6 = t & 63, ks8 = (t >> 6) * 8;
  int tok0 = tok_list[row0 + r6];       if ((unsigned)tok0 >= B_) tok0 = 0;
  int tok1 = tok_list[row0 + 64 + r6];  if ((unsigned)tok1 >= B_) tok1 = 0;
  const u16* a0 = xhi + (size_t)tok0 * D_ + ks8;
  const u16* a1 = xhi + (size_t)tok1 * D_ + ks8;
  const u16* bb0 = w1e + (size_t)(n0 + r6) * D_ + ks8;
  const u16* bb1 = w1e + (size_t)(n0 + 64 + r6) * D_ + ks8;

  const f32x4 z = {0.f, 0.f, 0.f, 0.f};
  f32x4 acc[4][4];
#pragma unroll
  for (int i = 0; i < 4; ++i)
#pragma unroll
    for (int j = 0; j < 4; ++j) acc[i][j] = z;

  // prologue: stage K-tile 0 into buf 0
  gload16(a0, &As[0][t * 8]);  gload16(a1, &As[0][2048 + t * 8]);
  gload16(bb0, &Bs[0][t * 8]); gload16(bb1, &Bs[0][2048 + t * 8]);
  __syncthreads();

  const int NT = D_ / 32;
  for (int kt = 0; kt < NT; ++kt) {
    const u16* Sa = As[kt & 1];
    const u16* Sb = Bs[kt & 1];
    if (kt + 1 < NT) {
      int k1 = (kt + 1) * 32;
      u16* Da = As[(kt + 1) & 1];
      u16* Db = Bs[(kt + 1) & 1];
      gload16(a0 + k1, &Da[t * 8]);  gload16(a1 + k1, &Da[2048 + t * 8]);
      gload16(bb0 + k1, &Db[t * 8]); gload16(bb1 + k1, &Db[2048 + t * 8]);
    }
    s16x8 af[4], bf[4];
#pragma unroll
    for (int i = 0; i < 4; ++i) {
      af[i] = *(const s16x8*)&Sa[frag_idx(wm, lane, i)];
      bf[i] = *(const s16x8*)&Sb[frag_idx(wn, lane, i)];
    }
#pragma unroll
    for (int i = 0; i < 4; ++i)
#pragma unroll
      for (int j = 0; j < 4; ++j)
        acc[i][j] = __builtin_amdgcn_mfma_f32_16x16x32_bf16(af[i], bf[j], acc[i][j], 0, 0, 0);
    __syncthreads();
  }
#pragma unroll
  for (int j = 0; j < 4; ++j) {
    int col = n0 + wn * 64 + j * 16 + (lane & 15);
    float bias = b1v[e * H_ + col];
#pragma unroll
    for (int i = 0; i < 4; ++i)
#pragma unroll
      for (int q = 0; q < 4; ++q) {
        int row = row0 + wm * 64 + i * 16 + (lane >> 4) * 4 + q;
        float v = acc[i][j][q] + bias;
        hbuf[(size_t)row * H_ + col] = f2bf(v > 0.f ? v : 0.f);
      }
  }
}

// ---------- expert GEMM2: rbuf[row] = w * (h @ W2[e] + b2[e]) (bf16, dbuf) ----------
__global__ __launch_bounds__(256) void k_egemm2(const u16* __restrict__ hbuf,
                                                const u16* __restrict__ w2t,
                                                const float* __restrict__ b2v,
                                                const int* __restrict__ aoff,
                                                const float* __restrict__ wroute,
                                                u16* __restrict__ rbuf) {
  __shared__ u16 As[2][4096], Bs[2][4096];
  int work = xcd_swz(blockIdx.x, (O_ / 128) * (ROWSP / 128));
  int rt = work >> 3;                 // row-tile (A-panel shared by 8 n-tiles)
  int n0 = (work & 7) * 128;
  int row0 = rt * 128;
  if (row0 >= aoff[8]) return;
  int e = 0;
  while (row0 >= aoff[e + 1]) ++e;
  int t = threadIdx.x, wave = t >> 6, lane = t & 63;
  int wm = wave >> 1, wn = wave & 1;
  const u16* w2e = w2t + (size_t)e * O_ * H_;

  int r6 = t & 63, ks8 = (t >> 6) * 8;
  const u16* a0 = hbuf + (size_t)(row0 + r6) * H_ + ks8;
  const u16* a1 = hbuf + (size_t)(row0 + 64 + r6) * H_ + ks8;
  const u16* bb0 = w2e + (size_t)(n0 + r6) * H_ + ks8;
  const u16* bb1 = w2e + (size_t)(n0 + 64 + r6) * H_ + ks8;

  const f32x4 z = {0.f, 0.f, 0.f, 0.f};
  f32x4 acc[4][4];
#pragma unroll
  for (int i = 0; i < 4; ++i)
#pragma unroll
    for (int j = 0; j < 4; ++j) acc[i][j] = z;

  gload16(a0, &As[0][t * 8]);  gload16(a1, &As[0][2048 + t * 8]);
  gload16(bb0, &Bs[0][t * 8]); gload16(bb1, &Bs[0][2048 + t * 8]);
  __syncthreads();

  const int NT = H_ / 32;
  for (int kt = 0; kt < NT; ++kt) {
    const u16* Sa = As[kt & 1];
    const u16* Sb = Bs[kt & 1];
    if (kt + 1 < NT) {
      int k1 = (kt + 1) * 32;
      u16* Da = As[(kt + 1) & 1];
      u16* Db = Bs[(kt + 1) & 1];
      gload16(a0 + k1, &Da[t * 8]);  gload16(a1 + k1, &Da[2048 + t * 8]);
      gload16(bb0 + k1, &Db[t * 8]); gload16(bb1 + k1, &Db[2048 + t * 8]);
    }
    s16x8 af[4], bf[4];
#pragma unroll
    for (int i = 0; i < 4; ++i) {
      af[i] = *(const s16x8*)&Sa[frag_idx(wm, lane, i)];
      bf[i] = *(const s16x8*)&Sb[frag_idx(wn, lane, i)];
    }
#pragma unroll
    for (int i = 0; i < 4; ++i)
#pragma unroll
      for (int j = 0; j < 4; ++j)
        acc[i][j] = __builtin_amdgcn_mfma_f32_16x16x32_bf16(af[i], bf[j], acc[i][j], 0, 0, 0);
    __syncthreads();
  }
#pragma unroll
  for (int i = 0; i < 4; ++i)
#pragma unroll
    for (int q = 0; q < 4; ++q) {
      int row = row0 + wm * 64 + i * 16 + (lane >> 4) * 4 + q;
      float wv = wroute[row];
#pragma unroll
      for (int j = 0; j < 4; ++j) {
        int col = n0 + wn * 64 + j * 16 + (lane & 15);
        float bias = b2v[e * O_ + col];
        rbuf[(size_t)row * O_ + col] = f2bf((acc[i][j][q] + bias) * wv);
      }
    }
}

// ---------- combine: out[tok] = rbuf[pos0] + rbuf[pos1] ----------
__global__ __launch_bounds__(256) void k_combine(const u16* __restrict__ rbuf,
                                                 const int* __restrict__ pos_of,
                                                 float* __restrict__ out) {
  int t = threadIdx.x;
  int tok = blockIdx.x * 2 + (t >> 7);
  int c = (t & 127) * 8;
  int p0 = pos_of[tok * 2], p1 = pos_of[tok * 2 + 1];
  const u16* r0 = rbuf + (size_t)p0 * O_ + c;
  const u16* r1 = rbuf + (size_t)p1 * O_ + c;
  ushort4 a0 = *(const ushort4*)r0, a1 = *(const ushort4*)(r0 + 4);
  ushort4 b0 = *(const ushort4*)r1, b1 = *(const ushort4*)(r1 + 4);
  float4 o0, o1;
  o0.x = bf2f(a0.x) + bf2f(b0.x); o0.y = bf2f(a0.y) + bf2f(b0.y);
  o0.z = bf2f(a0.z) + bf2f(b0.z); o0.w = bf2f(a0.w) + bf2f(b0.w);
  o1.x = bf2f(a1.x) + bf2f(b1.x); o1.y = bf2f(a1.y) + bf2f(b1.y);
  o1.z = bf2f(a1.z) + bf2f(b1.z); o1.w = bf2f(a1.w) + bf2f(b1.w);
  float* op = out + (size_t)tok * O_ + c;
  *(float4*)op = o0; *(float4*)(op + 4) = o1;
}

// ---------- workspace layout (bytes) ----------
static const size_t o_xhi  = 0;                                    // 16MB
static const size_t o_xlo  = o_xhi + (size_t)B_ * D_ * 2;          // 16MB
static const size_t o_w1t  = o_xlo + (size_t)B_ * D_ * 2;          // 32MB
static const size_t o_w2t  = o_w1t + (size_t)E_ * H_ * D_ * 2;     // 32MB
static const size_t o_wg1h = o_w2t + (size_t)E_ * O_ * H_ * 2;     // 1MB
static const size_t o_wg1l = o_wg1h + (size_t)G_ * D_ * 2;         // 1MB
static const size_t o_G1   = o_wg1l + (size_t)G_ * D_ * 2;         // 16MB
static const size_t o_h    = o_G1 + (size_t)B_ * G_ * 4;           // 68MB
static const size_t o_idx  = o_h + (size_t)ROWSP * H_ * 2;
static const size_t o_wn   = o_idx + (size_t)B_ * 2 * 4;
static const size_t o_pos  = o_wn + (size_t)B_ * 2 * 4;
static const size_t o_tok  = o_pos + (size_t)B_ * 2 * 4;
static const size_t o_wr   = o_tok + (size_t)ROWSP * 4;
static const size_t o_cnt  = o_wr + (size_t)ROWSP * 4;             // counts: 8 ints
static const size_t o_fill = o_cnt + 32;                           // fill: 8 ints
static const size_t o_ent  = o_cnt + 64;                           // entacc: 1 float
static const size_t o_nfl  = o_cnt + 96;                           // nflag: 1 int
static const size_t o_aoff = o_cnt + 128;                          // 9 ints
static const size_t o_logits = o_cnt + 256;                        // B*8 f32 = 256KB
static const size_t o_flag   = o_logits + (size_t)B_ * 8 * 4;      // B ints = 32KB
// rbuf (bf16, 35.7MB) aliases xlo+w1t — both dead before k_egemm2 runs,
// and rewritten by k_cast_x / k_transpose_cast at the start of every call.
static const size_t o_rbuf = o_xlo;                                // ends < o_w2t

extern "C" void kernel_launch(void* const* d_in, const int* in_sizes, int n_in,
                              void* d_out, int out_size, void* d_ws, size_t ws_size,
                              hipStream_t stream) {
  const float* x   = (const float*)d_in[0];
  const float* W1  = (const float*)d_in[1];
  const float* b1  = (const float*)d_in[2];
  const float* W2  = (const float*)d_in[3];
  const float* b2  = (const float*)d_in[4];
  const float* Wg1 = (const float*)d_in[5];
  const float* bg1 = (const float*)d_in[6];
  const float* Wg2 = (const float*)d_in[7];
  const float* bg2 = (const float*)d_in[8];
  float* out = (float*)d_out;
  char* ws = (char*)d_ws;

  u16* xhi  = (u16*)(ws + o_xhi);
  u16* xlo  = (u16*)(ws + o_xlo);
  u16* w1t  = (u16*)(ws + o_w1t);
  u16* w2t  = (u16*)(ws + o_w2t);
  u16* wg1h = (u16*)(ws + o_wg1h);
  u16* wg1l = (u16*)(ws + o_wg1l);
  float* G1 = (float*)(ws + o_G1);
  u16* hbuf = (u16*)(ws + o_h);
  int* topidx = (int*)(ws + o_idx);
  float* wnorm = (float*)(ws + o_wn);
  int* pos_of = (int*)(ws + o_pos);
  int* tok_list = (int*)(ws + o_tok);
  float* wroute = (float*)(ws + o_wr);
  int* counts = (int*)(ws + o_cnt);
  int* fill = (int*)(ws + o_fill);
  float* entacc = (float*)(ws + o_ent);
  int* nflag = (int*)(ws + o_nfl);
  int* aoff = (int*)(ws + o_aoff);
  float* logits = (float*)(ws + o_logits);
  int* flaglist = (int*)(ws + o_flag);
  u16* rbuf = (u16*)(ws + o_rbuf);

  hipMemsetAsync(ws + o_cnt, 0, 128, stream);

  k_cast_x<<<(B_ * D_ / 4) / 256, 256, 0, stream>>>(x, xhi, xlo);
  k_transpose_cast<<<dim3(G_ / 32, D_ / 32, 1), 256, 0, stream>>>(Wg1, wg1h, wg1l, D_, G_);
  k_transpose_cast<<<dim3(H_ / 32, D_ / 32, E_), 256, 0, stream>>>(W1, w1t, nullptr, D_, H_);
  k_transpose_cast<<<dim3(O_ / 32, H_ / 32, E_), 256, 0, stream>>>(W2, w2t, nullptr, H_, O_);

  k_gate_gemm1<<<(G_ / 128) * (B_ / 128), 256, 0, stream>>>(xhi, xlo, wg1h, wg1l, bg1, G1);
  k_gate_logits<<<B_ / 4, 256, 0, stream>>>(G1, Wg2, bg2, logits, flaglist, nflag);
  k_gate_fixup<<<128, 256, 0, stream>>>(x, Wg1, bg1, Wg2, bg2, flaglist, nflag, logits);
  k_gate_final<<<B_ / 256, 256, 0, stream>>>(logits, topidx, wnorm, counts, entacc);
  k_scan<<<1, 64, 0, stream>>>(counts, entacc, aoff, out + (size_t)B_ * O_);
  k_scatter<<<(B_ * 2) / 256, 256, 0, stream>>>(topidx, wnorm, aoff, fill, tok_list, wroute, pos_of);

  k_egemm1<<<(H_ / 128) * (ROWSP / 128), 256, 0, stream>>>(xhi, w1t, b1, tok_list, aoff, hbuf);
  k_egemm2<<<(O_ / 128) * (ROWSP / 128), 256, 0, stream>>>(hbuf, w2t, b2, aoff, wroute, rbuf);
  k_combine<<<B_ / 2, 256, 0, stream>>>(rbuf, pos_of, out);
}

// Round 5
// 514.672 us; speedup vs baseline: 1.2193x; 1.2193x over previous
//
#include <hip/hip_runtime.h>

#define B_ 8192
#define D_ 1024
#define O_ 1024
#define G_ 512
#define H_ 2048
#define E_ 8
#define ROWSP (B_ * 2 + E_ * 128)   // padded routed rows = 17408
#define TAU 0.01f

typedef unsigned short u16;
using f32x4 = __attribute__((ext_vector_type(4))) float;
using s16x8 = __attribute__((ext_vector_type(8))) short;

__device__ __forceinline__ u16 f2bf(float f) {
  union { float f; unsigned u; } v; v.f = f;
  unsigned r = v.u + 0x7FFFu + ((v.u >> 16) & 1u);
  return (u16)(r >> 16);
}
__device__ __forceinline__ float bf2f(u16 h) {
  union { unsigned u; float f; } v; v.u = ((unsigned)h) << 16; return v.f;
}
__device__ __forceinline__ void gload16(const void* g, void* l) {
  __builtin_amdgcn_global_load_lds(
      (const __attribute__((address_space(1))) unsigned int*)g,
      (__attribute__((address_space(3))) unsigned int*)l, 16, 0, 0);
}
// XCD-aware swizzle: hardware bid -> work id; XCD(bid)=bid%8 gets contiguous works.
__device__ __forceinline__ int xcd_swz(int bid, int nwg) {
  return (bid & 7) * (nwg >> 3) + (bid >> 3);
}
// Swizzled staging: thread li stages its row's k-chunk (li&3)^((li>>3)&3) to linear
// dest li*16B. Global set per row stays {0,1,2,3} -> full 64B contiguous (coalesced).
// Per-thread global column offset (u16):
__device__ __forceinline__ int stage_kc(int t) {
  return (((t & 3) ^ ((t >> 3) & 3)) * 8);
}
// Fragment read: for (row = half*64 + i*16 + (lane&15), ks = lane>>4), data sits at
// chunk row*4 + (ks ^ ((row>>1)&3)); ((row>>1)&3) == ((lane>>1)&3). u16 index:
__device__ __forceinline__ int frag_idx(int half, int lane, int i) {
  int row = half * 64 + i * 16 + (lane & 15);
  int s = (lane >> 4) ^ ((lane >> 1) & 3);
  return (row * 4 + s) * 8;
}

// ---------- cast x -> bf16 hi/lo ----------
__global__ __launch_bounds__(256) void k_cast_x(const float* __restrict__ x,
                                                u16* __restrict__ xhi,
                                                u16* __restrict__ xlo) {
  int t = blockIdx.x * 256 + threadIdx.x;  // < B_*D_/4
  float4 v = ((const float4*)x)[t];
  u16 h0 = f2bf(v.x), h1 = f2bf(v.y), h2 = f2bf(v.z), h3 = f2bf(v.w);
  ushort4 hi; hi.x = h0; hi.y = h1; hi.z = h2; hi.w = h3;
  ushort4 lo;
  lo.x = f2bf(v.x - bf2f(h0)); lo.y = f2bf(v.y - bf2f(h1));
  lo.z = f2bf(v.z - bf2f(h2)); lo.w = f2bf(v.w - bf2f(h3));
  ((ushort4*)xhi)[t] = hi; ((ushort4*)xlo)[t] = lo;
}

// ---------- transpose+cast: src [R][C] f32 -> dst [C][R] bf16 (hi, optional lo) ----------
__global__ __launch_bounds__(256) void k_transpose_cast(const float* __restrict__ src,
                                                        u16* __restrict__ dhi,
                                                        u16* __restrict__ dlo,
                                                        int R, int C) {
  __shared__ float tile[32][33];
  size_t bofs = (size_t)blockIdx.z * R * C;
  src += bofs; dhi += bofs; if (dlo) dlo += bofs;
  int tx = threadIdx.x & 31, ty = threadIdx.x >> 5;
  int c0 = blockIdx.x * 32, r0 = blockIdx.y * 32;
#pragma unroll
  for (int p = 0; p < 4; ++p) {
    int r = ty + p * 8;
    tile[r][tx] = src[(size_t)(r0 + r) * C + c0 + tx];
  }
  __syncthreads();
#pragma unroll
  for (int p = 0; p < 4; ++p) {
    int r = ty + p * 8;  // local C index
    float v = tile[tx][r];
    size_t o = (size_t)(c0 + r) * R + r0 + tx;
    dhi[o] = f2bf(v);
    if (dlo) dlo[o] = f2bf(v - bf2f(f2bf(v)));
  }
}

// ---------- gate GEMM1: G1 = relu(x @ Wg1 + bg1), 3-pass split bf16, f32 out ----------
__global__ __launch_bounds__(256) void k_gate_gemm1(const u16* __restrict__ xhi,
                                                    const u16* __restrict__ xlo,
                                                    const u16* __restrict__ whi,
                                                    const u16* __restrict__ wlo,
                                                    const float* __restrict__ bg1,
                                                    float* __restrict__ G1) {
  __shared__ u16 Ah[4096], Al[4096], Bh[4096], Bl[4096];
  int work = xcd_swz(blockIdx.x, (G_ / 128) * (B_ / 128));
  int m0 = (work >> 2) * 128, n0 = (work & 3) * 128;
  int t = threadIdx.x;
  int wave = t >> 6, lane = t & 63;
  int wm = wave >> 1, wn = wave & 1;

  const f32x4 z = {0.f, 0.f, 0.f, 0.f};
  f32x4 acc[4][4];
#pragma unroll
  for (int i = 0; i < 4; ++i)
#pragma unroll
    for (int j = 0; j < 4; ++j) acc[i][j] = z;

  int ar = t >> 2, ac = stage_kc(t);
  const u16* xh0 = xhi + (size_t)(m0 + ar) * D_ + ac;
  const u16* xh1 = xhi + (size_t)(m0 + 64 + ar) * D_ + ac;
  const u16* xl0 = xlo + (size_t)(m0 + ar) * D_ + ac;
  const u16* xl1 = xlo + (size_t)(m0 + 64 + ar) * D_ + ac;
  const u16* wh0 = whi + (size_t)(n0 + ar) * D_ + ac;
  const u16* wh1 = whi + (size_t)(n0 + 64 + ar) * D_ + ac;
  const u16* wl0 = wlo + (size_t)(n0 + ar) * D_ + ac;
  const u16* wl1 = wlo + (size_t)(n0 + 64 + ar) * D_ + ac;

  for (int k0 = 0; k0 < D_; k0 += 32) {
    gload16(xh0 + k0, &Ah[t * 8]); gload16(xh1 + k0, &Ah[2048 + t * 8]);
    gload16(xl0 + k0, &Al[t * 8]); gload16(xl1 + k0, &Al[2048 + t * 8]);
    gload16(wh0 + k0, &Bh[t * 8]); gload16(wh1 + k0, &Bh[2048 + t * 8]);
    gload16(wl0 + k0, &Bl[t * 8]); gload16(wl1 + k0, &Bl[2048 + t * 8]);
    __syncthreads();
    s16x8 ah[4], al[4], bh[4], bl[4];
#pragma unroll
    for (int i = 0; i < 4; ++i) {
      ah[i] = *(const s16x8*)&Ah[frag_idx(wm, lane, i)];
      al[i] = *(const s16x8*)&Al[frag_idx(wm, lane, i)];
      bh[i] = *(const s16x8*)&Bh[frag_idx(wn, lane, i)];
      bl[i] = *(const s16x8*)&Bl[frag_idx(wn, lane, i)];
    }
#pragma unroll
    for (int i = 0; i < 4; ++i)
#pragma unroll
      for (int j = 0; j < 4; ++j) {
        acc[i][j] = __builtin_amdgcn_mfma_f32_16x16x32_bf16(ah[i], bh[j], acc[i][j], 0, 0, 0);
        acc[i][j] = __builtin_amdgcn_mfma_f32_16x16x32_bf16(ah[i], bl[j], acc[i][j], 0, 0, 0);
        acc[i][j] = __builtin_amdgcn_mfma_f32_16x16x32_bf16(al[i], bh[j], acc[i][j], 0, 0, 0);
      }
    __syncthreads();
  }
#pragma unroll
  for (int j = 0; j < 4; ++j) {
    int col = n0 + wn * 64 + j * 16 + (lane & 15);
    float bias = bg1[col];
#pragma unroll
    for (int i = 0; i < 4; ++i)
#pragma unroll
      for (int q = 0; q < 4; ++q) {
        int row = m0 + wm * 64 + i * 16 + (lane >> 4) * 4 + q;
        float v = acc[i][j][q] + bias;
        G1[(size_t)row * G_ + col] = v > 0.f ? v : 0.f;
      }
  }
}

// ---------- gate logits: L = G1 @ Wg2 + bg2 (fp32, wave per row) + near-tie flagging ----------
__global__ __launch_bounds__(256) void k_gate_logits(const float* __restrict__ G1,
                                                     const float* __restrict__ Wg2,
                                                     const float* __restrict__ bg2,
                                                     float* __restrict__ logits,
                                                     int* __restrict__ flaglist,
                                                     int* __restrict__ nflag) {
  int t = threadIdx.x, wave = t >> 6, lane = t & 63;
  int row = blockIdx.x * 4 + wave;

  float4 g0 = *(const float4*)(G1 + (size_t)row * G_ + lane * 8);
  float4 g1 = *(const float4*)(G1 + (size_t)row * G_ + lane * 8 + 4);
  float g[8] = {g0.x, g0.y, g0.z, g0.w, g1.x, g1.y, g1.z, g1.w};
  float p[8] = {0, 0, 0, 0, 0, 0, 0, 0};
#pragma unroll
  for (int cc = 0; cc < 8; ++cc) {
    int c = lane * 8 + cc;
    float4 w0 = *(const float4*)(Wg2 + c * 8);
    float4 w1 = *(const float4*)(Wg2 + c * 8 + 4);
    p[0] += g[cc] * w0.x; p[1] += g[cc] * w0.y; p[2] += g[cc] * w0.z; p[3] += g[cc] * w0.w;
    p[4] += g[cc] * w1.x; p[5] += g[cc] * w1.y; p[6] += g[cc] * w1.z; p[7] += g[cc] * w1.w;
  }
#pragma unroll
  for (int off = 32; off >= 1; off >>= 1)
#pragma unroll
    for (int e = 0; e < 8; ++e) p[e] += __shfl_xor(p[e], off);
  if (lane == 0) {
    float l1 = -1e30f, l2 = -1e30f, l3 = -1e30f;
#pragma unroll
    for (int e = 0; e < 8; ++e) {
      float v = p[e] + bg2[e];
      logits[(size_t)row * 8 + e] = v;
      if (v > l1) { l3 = l2; l2 = l1; l1 = v; }
      else if (v > l2) { l3 = l2; l2 = v; }
      else if (v > l3) { l3 = v; }
    }
    if (l2 - l3 < TAU) {
      int pos = atomicAdd(nflag, 1);
      flaglist[pos] = row;
    }
  }
}

// ---------- exact fp32 recompute for flagged rows (tree reduce, no atomics) ----------
__global__ __launch_bounds__(256) void k_gate_fixup(const float* __restrict__ x,
                                                    const float* __restrict__ Wg1,
                                                    const float* __restrict__ bg1,
                                                    const float* __restrict__ Wg2,
                                                    const float* __restrict__ bg2,
                                                    const int* __restrict__ flaglist,
                                                    const int* __restrict__ nflag,
                                                    float* __restrict__ logits) {
  __shared__ float xs[1024];
  __shared__ float red[256][9];
  int t = threadIdx.x;
  int n = *nflag;
  for (int i = blockIdx.x; i < n; i += gridDim.x) {
    int row = flaglist[i];
    ((float4*)xs)[t] = ((const float4*)(x + (size_t)row * D_))[t];
    __syncthreads();
    int c0 = t * 2;
    float h0 = 0.f, h1 = 0.f;
#pragma unroll 8
    for (int d = 0; d < D_; ++d) {
      float xv = xs[d];
      float2 w = *(const float2*)(Wg1 + (size_t)d * G_ + c0);
      h0 += xv * w.x; h1 += xv * w.y;
    }
    h0 += bg1[c0]; h1 += bg1[c0 + 1];
    h0 = h0 > 0.f ? h0 : 0.f; h1 = h1 > 0.f ? h1 : 0.f;
#pragma unroll
    for (int e = 0; e < 8; ++e)
      red[t][e] = h0 * Wg2[c0 * 8 + e] + h1 * Wg2[(c0 + 1) * 8 + e];
    __syncthreads();
    for (int s = 128; s >= 1; s >>= 1) {
      if (t < s) {
#pragma unroll
        for (int e = 0; e < 8; ++e) red[t][e] += red[t + s][e];
      }
      __syncthreads();
    }
    if (t < 8) logits[(size_t)row * 8 + t] = red[0][t] + bg2[t];
    __syncthreads();
  }
}

// ---------- final gate: softmax + top2 + weights + counts/entropy (thread per row) ----------
__global__ __launch_bounds__(256) void k_gate_final(const float* __restrict__ logits,
                                                    int* __restrict__ topidx,
                                                    float* __restrict__ wnorm,
                                                    int* __restrict__ counts,
                                                    float* __restrict__ entacc) {
  __shared__ int cnt_s[8];
  __shared__ float ent_s[4];
  int t = threadIdx.x;
  if (t < 8) cnt_s[t] = 0;
  __syncthreads();
  int row = blockIdx.x * 256 + t;
  float4 a = ((const float4*)logits)[(size_t)row * 2];
  float4 b = ((const float4*)logits)[(size_t)row * 2 + 1];
  float L[8] = {a.x, a.y, a.z, a.w, b.x, b.y, b.z, b.w};
  float m = L[0];
#pragma unroll
  for (int e = 1; e < 8; ++e) m = fmaxf(m, L[e]);
  float s[8], Z = 0.f;
#pragma unroll
  for (int e = 0; e < 8; ++e) { s[e] = expf(L[e] - m); Z += s[e]; }
  float inv = 1.f / Z;
  float sc[8];
#pragma unroll
  for (int e = 0; e < 8; ++e) sc[e] = s[e] * inv;
  int i1 = 0;
#pragma unroll
  for (int e = 1; e < 8; ++e) if (L[e] > L[i1]) i1 = e;
  int i2 = (i1 == 0) ? 1 : 0;
#pragma unroll
  for (int e = 0; e < 8; ++e) if (e != i1 && L[e] > L[i2]) i2 = e;
  float s1 = sc[i1], s2 = sc[i2];
  float denom = s1 + s2 + 1e-9f;
  topidx[row * 2] = i1; topidx[row * 2 + 1] = i2;
  wnorm[row * 2] = s1 / denom; wnorm[row * 2 + 1] = s2 / denom;
  atomicAdd(&cnt_s[i1], 1); atomicAdd(&cnt_s[i2], 1);
  float ent = 0.f;
#pragma unroll
  for (int e = 0; e < 8; ++e) ent -= sc[e] * logf(sc[e] + 1e-9f);
#pragma unroll
  for (int off = 32; off >= 1; off >>= 1) ent += __shfl_xor(ent, off);
  if ((t & 63) == 0) ent_s[t >> 6] = ent;
  __syncthreads();
  if (t == 0) atomicAdd(entacc, ent_s[0] + ent_s[1] + ent_s[2] + ent_s[3]);
  if (t < 8) atomicAdd(&counts[t], cnt_s[t]);
}

// ---------- scan: padded offsets + aux loss ----------
__global__ void k_scan(const int* __restrict__ counts, const float* __restrict__ entacc,
                       int* __restrict__ aoff, float* __restrict__ aux_out) {
  if (threadIdx.x == 0 && blockIdx.x == 0) {
    int off = 0; aoff[0] = 0;
    float ld[8]; float mean = 0.f;
    for (int e = 0; e < 8; ++e) {
      ld[e] = (float)counts[e] / (8192.0f + 1e-9f);
      mean += ld[e];
      off += ((counts[e] + 127) >> 7) << 7;
      aoff[e + 1] = off;
    }
    mean *= 0.125f;
    float var = 0.f;
    for (int e = 0; e < 8; ++e) { float d = ld[e] - mean; var += d * d; }
    var *= (1.0f / 7.0f);
    *aux_out = var + entacc[0] / 8192.0f;
  }
}

// ---------- scatter routing (+ per-(token,k) position record) ----------
__global__ __launch_bounds__(256) void k_scatter(const int* __restrict__ topidx,
                                                 const float* __restrict__ wnorm,
                                                 const int* __restrict__ aoff,
                                                 int* __restrict__ fill,
                                                 int* __restrict__ tok_list,
                                                 float* __restrict__ wroute,
                                                 int* __restrict__ pos_of) {
  int t = blockIdx.x * 256 + threadIdx.x;
  if (t >= B_ * 2) return;
  int e = topidx[t];
  int pos = aoff[e] + atomicAdd(&fill[e], 1);
  tok_list[pos] = t >> 1;
  wroute[pos] = wnorm[t];
  pos_of[t] = pos;
}

// ---------- expert GEMM1: h = relu(gather(x) @ W1[e] + b1[e]) -> bf16 (dbuf) ----------
__global__ __launch_bounds__(256) void k_egemm1(const u16* __restrict__ xhi,
                                                const u16* __restrict__ w1t,
                                                const float* __restrict__ b1v,
                                                const int* __restrict__ tok_list,
                                                const int* __restrict__ aoff,
                                                u16* __restrict__ hbuf) {
  __shared__ u16 As[2][4096], Bs[2][4096];
  int work = xcd_swz(blockIdx.x, (H_ / 128) * (ROWSP / 128));
  int rt = work >> 4;                 // row-tile (A-panel shared by 16 n-tiles)
  int n0 = (work & 15) * 128;
  int row0 = rt * 128;
  if (row0 >= aoff[8]) return;
  int e = 0;
  while (row0 >= aoff[e + 1]) ++e;
  int t = threadIdx.x, wave = t >> 6, lane = t & 63;
  int wm = wave >> 1, wn = wave & 1;
  const u16* w1e = w1t + (size_t)e * H_ * D_;

  int ar = t >> 2, ac = stage_kc(t);
  int tok0 = tok_list[row0 + ar];       if ((unsigned)tok0 >= B_) tok0 = 0;
  int tok1 = tok_list[row0 + 64 + ar];  if ((unsigned)tok1 >= B_) tok1 = 0;
  const u16* a0 = xhi + (size_t)tok0 * D_ + ac;
  const u16* a1 = xhi + (size_t)tok1 * D_ + ac;
  const u16* bb0 = w1e + (size_t)(n0 + ar) * D_ + ac;
  const u16* bb1 = w1e + (size_t)(n0 + 64 + ar) * D_ + ac;

  const f32x4 z = {0.f, 0.f, 0.f, 0.f};
  f32x4 acc[4][4];
#pragma unroll
  for (int i = 0; i < 4; ++i)
#pragma unroll
    for (int j = 0; j < 4; ++j) acc[i][j] = z;

  // prologue: stage K-tile 0 into buf 0
  gload16(a0, &As[0][t * 8]);  gload16(a1, &As[0][2048 + t * 8]);
  gload16(bb0, &Bs[0][t * 8]); gload16(bb1, &Bs[0][2048 + t * 8]);
  __syncthreads();

  const int NT = D_ / 32;
  for (int kt = 0; kt < NT; ++kt) {
    const u16* Sa = As[kt & 1];
    const u16* Sb = Bs[kt & 1];
    if (kt + 1 < NT) {
      int k1 = (kt + 1) * 32;
      u16* Da = As[(kt + 1) & 1];
      u16* Db = Bs[(kt + 1) & 1];
      gload16(a0 + k1, &Da[t * 8]);  gload16(a1 + k1, &Da[2048 + t * 8]);
      gload16(bb0 + k1, &Db[t * 8]); gload16(bb1 + k1, &Db[2048 + t * 8]);
    }
    s16x8 af[4], bf[4];
#pragma unroll
    for (int i = 0; i < 4; ++i) {
      af[i] = *(const s16x8*)&Sa[frag_idx(wm, lane, i)];
      bf[i] = *(const s16x8*)&Sb[frag_idx(wn, lane, i)];
    }
#pragma unroll
    for (int i = 0; i < 4; ++i)
#pragma unroll
      for (int j = 0; j < 4; ++j)
        acc[i][j] = __builtin_amdgcn_mfma_f32_16x16x32_bf16(af[i], bf[j], acc[i][j], 0, 0, 0);
    __syncthreads();
  }
#pragma unroll
  for (int j = 0; j < 4; ++j) {
    int col = n0 + wn * 64 + j * 16 + (lane & 15);
    float bias = b1v[e * H_ + col];
#pragma unroll
    for (int i = 0; i < 4; ++i)
#pragma unroll
      for (int q = 0; q < 4; ++q) {
        int row = row0 + wm * 64 + i * 16 + (lane >> 4) * 4 + q;
        float v = acc[i][j][q] + bias;
        hbuf[(size_t)row * H_ + col] = f2bf(v > 0.f ? v : 0.f);
      }
  }
}

// ---------- expert GEMM2: rbuf[row] = w * (h @ W2[e] + b2[e]) (bf16, dbuf) ----------
__global__ __launch_bounds__(256) void k_egemm2(const u16* __restrict__ hbuf,
                                                const u16* __restrict__ w2t,
                                                const float* __restrict__ b2v,
                                                const int* __restrict__ aoff,
                                                const float* __restrict__ wroute,
                                                u16* __restrict__ rbuf) {
  __shared__ u16 As[2][4096], Bs[2][4096];
  int work = xcd_swz(blockIdx.x, (O_ / 128) * (ROWSP / 128));
  int rt = work >> 3;                 // row-tile (A-panel shared by 8 n-tiles)
  int n0 = (work & 7) * 128;
  int row0 = rt * 128;
  if (row0 >= aoff[8]) return;
  int e = 0;
  while (row0 >= aoff[e + 1]) ++e;
  int t = threadIdx.x, wave = t >> 6, lane = t & 63;
  int wm = wave >> 1, wn = wave & 1;
  const u16* w2e = w2t + (size_t)e * O_ * H_;

  int ar = t >> 2, ac = stage_kc(t);
  const u16* a0 = hbuf + (size_t)(row0 + ar) * H_ + ac;
  const u16* a1 = hbuf + (size_t)(row0 + 64 + ar) * H_ + ac;
  const u16* bb0 = w2e + (size_t)(n0 + ar) * H_ + ac;
  const u16* bb1 = w2e + (size_t)(n0 + 64 + ar) * H_ + ac;

  const f32x4 z = {0.f, 0.f, 0.f, 0.f};
  f32x4 acc[4][4];
#pragma unroll
  for (int i = 0; i < 4; ++i)
#pragma unroll
    for (int j = 0; j < 4; ++j) acc[i][j] = z;

  gload16(a0, &As[0][t * 8]);  gload16(a1, &As[0][2048 + t * 8]);
  gload16(bb0, &Bs[0][t * 8]); gload16(bb1, &Bs[0][2048 + t * 8]);
  __syncthreads();

  const int NT = H_ / 32;
  for (int kt = 0; kt < NT; ++kt) {
    const u16* Sa = As[kt & 1];
    const u16* Sb = Bs[kt & 1];
    if (kt + 1 < NT) {
      int k1 = (kt + 1) * 32;
      u16* Da = As[(kt + 1) & 1];
      u16* Db = Bs[(kt + 1) & 1];
      gload16(a0 + k1, &Da[t * 8]);  gload16(a1 + k1, &Da[2048 + t * 8]);
      gload16(bb0 + k1, &Db[t * 8]); gload16(bb1 + k1, &Db[2048 + t * 8]);
    }
    s16x8 af[4], bf[4];
#pragma unroll
    for (int i = 0; i < 4; ++i) {
      af[i] = *(const s16x8*)&Sa[frag_idx(wm, lane, i)];
      bf[i] = *(const s16x8*)&Sb[frag_idx(wn, lane, i)];
    }
#pragma unroll
    for (int i = 0; i < 4; ++i)
#pragma unroll
      for (int j = 0; j < 4; ++j)
        acc[i][j] = __builtin_amdgcn_mfma_f32_16x16x32_bf16(af[i], bf[j], acc[i][j], 0, 0, 0);
    __syncthreads();
  }
#pragma unroll
  for (int i = 0; i < 4; ++i)
#pragma unroll
    for (int q = 0; q < 4; ++q) {
      int row = row0 + wm * 64 + i * 16 + (lane >> 4) * 4 + q;
      float wv = wroute[row];
#pragma unroll
      for (int j = 0; j < 4; ++j) {
        int col = n0 + wn * 64 + j * 16 + (lane & 15);
        float bias = b2v[e * O_ + col];
        rbuf[(size_t)row * O_ + col] = f2bf((acc[i][j][q] + bias) * wv);
      }
    }
}

// ---------- combine: out[tok] = rbuf[pos0] + rbuf[pos1] ----------
__global__ __launch_bounds__(256) void k_combine(const u16* __restrict__ rbuf,
                                                 const int* __restrict__ pos_of,
                                                 float* __restrict__ out) {
  int t = threadIdx.x;
  int tok = blockIdx.x * 2 + (t >> 7);
  int c = (t & 127) * 8;
  int p0 = pos_of[tok * 2], p1 = pos_of[tok * 2 + 1];
  const u16* r0 = rbuf + (size_t)p0 * O_ + c;
  const u16* r1 = rbuf + (size_t)p1 * O_ + c;
  ushort4 a0 = *(const ushort4*)r0, a1 = *(const ushort4*)(r0 + 4);
  ushort4 b0 = *(const ushort4*)r1, b1 = *(const ushort4*)(r1 + 4);
  float4 o0, o1;
  o0.x = bf2f(a0.x) + bf2f(b0.x); o0.y = bf2f(a0.y) + bf2f(b0.y);
  o0.z = bf2f(a0.z) + bf2f(b0.z); o0.w = bf2f(a0.w) + bf2f(b0.w);
  o1.x = bf2f(a1.x) + bf2f(b1.x); o1.y = bf2f(a1.y) + bf2f(b1.y);
  o1.z = bf2f(a1.z) + bf2f(b1.z); o1.w = bf2f(a1.w) + bf2f(b1.w);
  float* op = out + (size_t)tok * O_ + c;
  *(float4*)op = o0; *(float4*)(op + 4) = o1;
}

// ---------- workspace layout (bytes) ----------
static const size_t o_xhi  = 0;                                    // 16MB
static const size_t o_xlo  = o_xhi + (size_t)B_ * D_ * 2;          // 16MB
static const size_t o_w1t  = o_xlo + (size_t)B_ * D_ * 2;          // 32MB
static const size_t o_w2t  = o_w1t + (size_t)E_ * H_ * D_ * 2;     // 32MB
static const size_t o_wg1h = o_w2t + (size_t)E_ * O_ * H_ * 2;     // 1MB
static const size_t o_wg1l = o_wg1h + (size_t)G_ * D_ * 2;         // 1MB
static const size_t o_G1   = o_wg1l + (size_t)G_ * D_ * 2;         // 16MB
static const size_t o_h    = o_G1 + (size_t)B_ * G_ * 4;           // 68MB
static const size_t o_idx  = o_h + (size_t)ROWSP * H_ * 2;
static const size_t o_wn   = o_idx + (size_t)B_ * 2 * 4;
static const size_t o_pos  = o_wn + (size_t)B_ * 2 * 4;
static const size_t o_tok  = o_pos + (size_t)B_ * 2 * 4;
static const size_t o_wr   = o_tok + (size_t)ROWSP * 4;
static const size_t o_cnt  = o_wr + (size_t)ROWSP * 4;             // counts: 8 ints
static const size_t o_fill = o_cnt + 32;                           // fill: 8 ints
static const size_t o_ent  = o_cnt + 64;                           // entacc: 1 float
static const size_t o_nfl  = o_cnt + 96;                           // nflag: 1 int
static const size_t o_aoff = o_cnt + 128;                          // 9 ints
static const size_t o_logits = o_cnt + 256;                        // B*8 f32 = 256KB
static const size_t o_flag   = o_logits + (size_t)B_ * 8 * 4;      // B ints = 32KB
// rbuf (bf16, 35.7MB) aliases xlo+w1t — both dead before k_egemm2 runs,
// and rewritten by k_cast_x / k_transpose_cast at the start of every call.
static const size_t o_rbuf = o_xlo;                                // ends < o_w2t

extern "C" void kernel_launch(void* const* d_in, const int* in_sizes, int n_in,
                              void* d_out, int out_size, void* d_ws, size_t ws_size,
                              hipStream_t stream) {
  const float* x   = (const float*)d_in[0];
  const float* W1  = (const float*)d_in[1];
  const float* b1  = (const float*)d_in[2];
  const float* W2  = (const float*)d_in[3];
  const float* b2  = (const float*)d_in[4];
  const float* Wg1 = (const float*)d_in[5];
  const float* bg1 = (const float*)d_in[6];
  const float* Wg2 = (const float*)d_in[7];
  const float* bg2 = (const float*)d_in[8];
  float* out = (float*)d_out;
  char* ws = (char*)d_ws;

  u16* xhi  = (u16*)(ws + o_xhi);
  u16* xlo  = (u16*)(ws + o_xlo);
  u16* w1t  = (u16*)(ws + o_w1t);
  u16* w2t  = (u16*)(ws + o_w2t);
  u16* wg1h = (u16*)(ws + o_wg1h);
  u16* wg1l = (u16*)(ws + o_wg1l);
  float* G1 = (float*)(ws + o_G1);
  u16* hbuf = (u16*)(ws + o_h);
  int* topidx = (int*)(ws + o_idx);
  float* wnorm = (float*)(ws + o_wn);
  int* pos_of = (int*)(ws + o_pos);
  int* tok_list = (int*)(ws + o_tok);
  float* wroute = (float*)(ws + o_wr);
  int* counts = (int*)(ws + o_cnt);
  int* fill = (int*)(ws + o_fill);
  float* entacc = (float*)(ws + o_ent);
  int* nflag = (int*)(ws + o_nfl);
  int* aoff = (int*)(ws + o_aoff);
  float* logits = (float*)(ws + o_logits);
  int* flaglist = (int*)(ws + o_flag);
  u16* rbuf = (u16*)(ws + o_rbuf);

  hipMemsetAsync(ws + o_cnt, 0, 128, stream);

  k_cast_x<<<(B_ * D_ / 4) / 256, 256, 0, stream>>>(x, xhi, xlo);
  k_transpose_cast<<<dim3(G_ / 32, D_ / 32, 1), 256, 0, stream>>>(Wg1, wg1h, wg1l, D_, G_);
  k_transpose_cast<<<dim3(H_ / 32, D_ / 32, E_), 256, 0, stream>>>(W1, w1t, nullptr, D_, H_);
  k_transpose_cast<<<dim3(O_ / 32, H_ / 32, E_), 256, 0, stream>>>(W2, w2t, nullptr, H_, O_);

  k_gate_gemm1<<<(G_ / 128) * (B_ / 128), 256, 0, stream>>>(xhi, xlo, wg1h, wg1l, bg1, G1);
  k_gate_logits<<<B_ / 4, 256, 0, stream>>>(G1, Wg2, bg2, logits, flaglist, nflag);
  k_gate_fixup<<<128, 256, 0, stream>>>(x, Wg1, bg1, Wg2, bg2, flaglist, nflag, logits);
  k_gate_final<<<B_ / 256, 256, 0, stream>>>(logits, topidx, wnorm, counts, entacc);
  k_scan<<<1, 64, 0, stream>>>(counts, entacc, aoff, out + (size_t)B_ * O_);
  k_scatter<<<(B_ * 2) / 256, 256, 0, stream>>>(topidx, wnorm, aoff, fill, tok_list, wroute, pos_of);

  k_egemm1<<<(H_ / 128) * (ROWSP / 128), 256, 0, stream>>>(xhi, w1t, b1, tok_list, aoff, hbuf);
  k_egemm2<<<(O_ / 128) * (ROWSP / 128), 256, 0, stream>>>(hbuf, w2t, b2, aoff, wroute, rbuf);
  k_combine<<<B_ / 2, 256, 0, stream>>>(rbuf, pos_of, out);
}